// Round 1
// baseline (502.883 us; speedup 1.0000x reference)
//
#include <hip/hip_runtime.h>
#include <math.h>

// Shapes (fixed by the reference)
#define B_    512
#define T_    512
#define DEC_  128
#define EMB_  512
#define VOC_  30001
#define VEXT_ 30051   // VOC_ + 50 OOV

typedef float f32x4 __attribute__((ext_vector_type(4)));
typedef short s16x4 __attribute__((ext_vector_type(4)));

#define L2E 1.4426950408889634f

__device__ __forceinline__ float sigmoid_f(float x) {
  float xc = fminf(fmaxf(x, -30.f), 30.f);
  float t = exp2f(xc * L2E);
  return t / (1.f + t);
}
__device__ __forceinline__ float tanh_f(float x) {
  float xc = fminf(fmaxf(x, -15.f), 15.f);
  float t = exp2f(xc * (2.f * L2E));
  return (t - 1.f) / (t + 1.f);
}
// f32 -> bf16 (RNE)
__device__ __forceinline__ short f2bf(float f) {
  unsigned u = __builtin_bit_cast(unsigned, f);
  u += 0x7FFFu + ((u >> 16) & 1u);
  return (short)(u >> 16);
}

// ---------------------------------------------------------------------------
// K1: x1[b,f] = sum_k [emb[x[b]] | ctx_prev][b,k] * W1_w[f,k] + W1_b[f]
// M=512(b), N=512(f), K=640. 32x32 tiles, fp32.
// ---------------------------------------------------------------------------
__global__ __launch_bounds__(256) void k1_x1(
    const float* __restrict__ emb, const int* __restrict__ x,
    const float* __restrict__ ctxp, const float* __restrict__ W1w,
    const float* __restrict__ W1b, float* __restrict__ x1) {
  __shared__ float As[32][33];
  __shared__ float Ws[32][33];
  const int tid = threadIdx.x;
  const int f0 = blockIdx.x * 32, b0 = blockIdx.y * 32;
  const int row = tid >> 3, seg = tid & 7;
  const int tx = tid & 15, ty = tid >> 4;
  float a00 = 0.f, a01 = 0.f, a10 = 0.f, a11 = 0.f;
  for (int k0 = 0; k0 < 640; k0 += 32) {
    int k = k0 + seg * 4;
    f32x4 av;
    if (k < 512) {
      int xb = x[b0 + row];
      av = *(const f32x4*)(emb + xb * 512 + k);
    } else {
      av = *(const f32x4*)(ctxp + (b0 + row) * 128 + (k - 512));
    }
    As[row][seg * 4 + 0] = av[0]; As[row][seg * 4 + 1] = av[1];
    As[row][seg * 4 + 2] = av[2]; As[row][seg * 4 + 3] = av[3];
    f32x4 wv = *(const f32x4*)(W1w + (f0 + row) * 640 + k);
    Ws[row][seg * 4 + 0] = wv[0]; Ws[row][seg * 4 + 1] = wv[1];
    Ws[row][seg * 4 + 2] = wv[2]; Ws[row][seg * 4 + 3] = wv[3];
    __syncthreads();
#pragma unroll
    for (int kk = 0; kk < 32; ++kk) {
      float v0 = As[ty * 2][kk], v1 = As[ty * 2 + 1][kk];
      float w0 = Ws[tx * 2][kk], w1 = Ws[tx * 2 + 1][kk];
      a00 += v0 * w0; a01 += v0 * w1; a10 += v1 * w0; a11 += v1 * w1;
    }
    __syncthreads();
  }
  int fo = f0 + tx * 2, bo = b0 + ty * 2;
  x1[bo * 512 + fo]           = a00 + W1b[fo];
  x1[bo * 512 + fo + 1]       = a01 + W1b[fo + 1];
  x1[(bo + 1) * 512 + fo]     = a10 + W1b[fo];
  x1[(bo + 1) * 512 + fo + 1] = a11 + W1b[fo + 1];
}

// ---------------------------------------------------------------------------
// K2: gates[b,j] = sum [x1 | h_prev][b,k] * [W_ih | W_hh][j,k] + b_ih + b_hh
// ---------------------------------------------------------------------------
__global__ __launch_bounds__(256) void k2_gates(
    const float* __restrict__ x1, const float* __restrict__ hprev,
    const float* __restrict__ Wih, const float* __restrict__ Whh,
    const float* __restrict__ bih, const float* __restrict__ bhh,
    float* __restrict__ gates) {
  __shared__ float As[32][33];
  __shared__ float Ws[32][33];
  const int tid = threadIdx.x;
  const int f0 = blockIdx.x * 32, b0 = blockIdx.y * 32;
  const int row = tid >> 3, seg = tid & 7;
  const int tx = tid & 15, ty = tid >> 4;
  float a00 = 0.f, a01 = 0.f, a10 = 0.f, a11 = 0.f;
  for (int k0 = 0; k0 < 640; k0 += 32) {
    int k = k0 + seg * 4;
    f32x4 av, wv;
    if (k < 512) {
      av = *(const f32x4*)(x1 + (b0 + row) * 512 + k);
      wv = *(const f32x4*)(Wih + (f0 + row) * 512 + k);
    } else {
      av = *(const f32x4*)(hprev + (b0 + row) * 128 + (k - 512));
      wv = *(const f32x4*)(Whh + (f0 + row) * 128 + (k - 512));
    }
    As[row][seg * 4 + 0] = av[0]; As[row][seg * 4 + 1] = av[1];
    As[row][seg * 4 + 2] = av[2]; As[row][seg * 4 + 3] = av[3];
    Ws[row][seg * 4 + 0] = wv[0]; Ws[row][seg * 4 + 1] = wv[1];
    Ws[row][seg * 4 + 2] = wv[2]; Ws[row][seg * 4 + 3] = wv[3];
    __syncthreads();
#pragma unroll
    for (int kk = 0; kk < 32; ++kk) {
      float v0 = As[ty * 2][kk], v1 = As[ty * 2 + 1][kk];
      float w0 = Ws[tx * 2][kk], w1 = Ws[tx * 2 + 1][kk];
      a00 += v0 * w0; a01 += v0 * w1; a10 += v1 * w0; a11 += v1 * w1;
    }
    __syncthreads();
  }
  int fo = f0 + tx * 2, bo = b0 + ty * 2;
  gates[bo * 512 + fo]           = a00 + bih[fo] + bhh[fo];
  gates[bo * 512 + fo + 1]       = a01 + bih[fo + 1] + bhh[fo + 1];
  gates[(bo + 1) * 512 + fo]     = a10 + bih[fo] + bhh[fo];
  gates[(bo + 1) * 512 + fo + 1] = a11 + bih[fo + 1] + bhh[fo + 1];
}

// ---------------------------------------------------------------------------
// K3: LSTM cell + dec_f = s_t @ Ws_w^T + Ws_b.  One block per b, 128 threads.
// ---------------------------------------------------------------------------
__global__ __launch_bounds__(128) void k3_lstm(
    const float* __restrict__ gates, const float* __restrict__ cprev,
    const float* __restrict__ Wsw, const float* __restrict__ Wsb,
    float* __restrict__ out_h, float* __restrict__ out_c,
    float* __restrict__ decf) {
  __shared__ float st[256];
  int b = blockIdx.x, d = threadIdx.x;
  const float* g = gates + b * 512;
  float iv = sigmoid_f(g[d]);
  float fv = sigmoid_f(g[128 + d]);
  float gv = tanh_f(g[256 + d]);
  float ov = sigmoid_f(g[384 + d]);
  float c = fv * cprev[b * 128 + d] + iv * gv;
  float h = ov * tanh_f(c);
  out_h[b * 128 + d] = h;
  out_c[b * 128 + d] = c;
  st[d] = h; st[128 + d] = c;
  __syncthreads();
  float acc = Wsb[d];
  const float* wr = Wsw + d * 256;
#pragma unroll 4
  for (int k = 0; k < 256; ++k) acc += st[k] * wr[k];
  decf[b * 128 + d] = acc;
}

// ---------------------------------------------------------------------------
// K4: e_t[b,t] = V_w . tanh(h_i@Wh^T + dec_f[b] + cov[b,t]*Wc)
// MFMA 16x16x16 bf16 (_1k). One wave handles (b, 64 t, all 128 d).
// grid = 1024 (= B*2), block = 256 (4 waves).
// ---------------------------------------------------------------------------
__global__ __launch_bounds__(256) void k4_et(
    const float* __restrict__ h_i, const float* __restrict__ Whw,
    const float* __restrict__ decf, const float* __restrict__ cov,
    const float* __restrict__ Wcw, const float* __restrict__ Vw,
    float* __restrict__ e_t) {
  const int b = blockIdx.x >> 1;
  const int th = blockIdx.x & 1;
  const int wv = threadIdx.x >> 6;
  const int lane = threadIdx.x & 63;
  const int lm = lane & 15, lg = lane >> 4;
  const int t0 = th * 256 + wv * 64;

  // A fragments: h_i rows. afr[mf][kf]: A[i=lm][k=4*lg+e], k-tile kf (K=16)
  s16x4 afr[4][8];
#pragma unroll
  for (int mf = 0; mf < 4; ++mf) {
#pragma unroll
    for (int kf = 0; kf < 8; ++kf) {
      const float* p = h_i + (size_t)(b * 512 + t0 + mf * 16 + lm) * 128 + kf * 16 + lg * 4;
      f32x4 v = *(const f32x4*)p;
      s16x4 a; a[0] = f2bf(v[0]); a[1] = f2bf(v[1]); a[2] = f2bf(v[2]); a[3] = f2bf(v[3]);
      afr[mf][kf] = a;
    }
  }
  float dec_v[8], vw_v[8], wc_v[8];
#pragma unroll
  for (int nf = 0; nf < 8; ++nf) {
    dec_v[nf] = decf[b * 128 + nf * 16 + lm];
    vw_v[nf]  = Vw[nf * 16 + lm];
    wc_v[nf]  = Wcw[nf * 16 + lm];
  }
  float cov_v[16];
#pragma unroll
  for (int mf = 0; mf < 4; ++mf)
#pragma unroll
    for (int r = 0; r < 4; ++r)
      cov_v[mf * 4 + r] = cov[b * 512 + t0 + mf * 16 + lg * 4 + r];

  float e_acc[16];
#pragma unroll
  for (int i = 0; i < 16; ++i) e_acc[i] = 0.f;

  const f32x4 zf4 = {0.f, 0.f, 0.f, 0.f};
  for (int nf = 0; nf < 8; ++nf) {
    f32x4 acc[4];
#pragma unroll
    for (int mf = 0; mf < 4; ++mf) acc[mf] = zf4;
#pragma unroll
    for (int kf = 0; kf < 8; ++kf) {
      // B[k=4*lg+e][n=lm] = Wh_w[n][k]  (enc = h_i @ Wh^T)
      const float* q = Whw + (nf * 16 + lm) * 128 + kf * 16 + lg * 4;
      f32x4 w = *(const f32x4*)q;
      s16x4 bf_; bf_[0] = f2bf(w[0]); bf_[1] = f2bf(w[1]); bf_[2] = f2bf(w[2]); bf_[3] = f2bf(w[3]);
#pragma unroll
      for (int mf = 0; mf < 4; ++mf)
        acc[mf] = __builtin_amdgcn_mfma_f32_16x16x16bf16_1k(afr[mf][kf], bf_, acc[mf], 0, 0, 0);
    }
    // D[i=4*lg+r][j=lm]: t = t0+mf*16+4*lg+r, d = nf*16+lm
#pragma unroll
    for (int mf = 0; mf < 4; ++mf)
#pragma unroll
      for (int r = 0; r < 4; ++r) {
        float val = acc[mf][r] + dec_v[nf] + cov_v[mf * 4 + r] * wc_v[nf];
        e_acc[mf * 4 + r] += vw_v[nf] * tanh_f(val);
      }
  }
  // reduce over the 16 d-columns held across lanes lm=0..15 (same lg group)
#pragma unroll
  for (int i = 0; i < 16; ++i) {
    float v = e_acc[i];
    v += __shfl_xor(v, 1); v += __shfl_xor(v, 2);
    v += __shfl_xor(v, 4); v += __shfl_xor(v, 8);
    e_acc[i] = v;
  }
  if (lm == 0) {
#pragma unroll
    for (int mf = 0; mf < 4; ++mf)
#pragma unroll
      for (int r = 0; r < 4; ++r)
        e_t[b * 512 + t0 + mf * 16 + lg * 4 + r] = e_acc[mf * 4 + r];
  }
}

// ---------------------------------------------------------------------------
// K5: softmax over t, coverage_new, ctx = sum_t a_t * h_i. One block per b.
// ---------------------------------------------------------------------------
__global__ __launch_bounds__(256) void k5_softmax_ctx(
    const float* __restrict__ e_t, const float* __restrict__ cov,
    const float* __restrict__ h_i, float* __restrict__ a_t,
    float* __restrict__ cov_out, float* __restrict__ ctx_out) {
  __shared__ float sm[512];
  __shared__ float red[256];
  __shared__ float wred[8];
  int b = blockIdx.x, tid = threadIdx.x;
  float e0 = e_t[b * 512 + tid], e1 = e_t[b * 512 + 256 + tid];
  float m = fmaxf(e0, e1);
  for (int off = 32; off; off >>= 1) m = fmaxf(m, __shfl_xor(m, off));
  if ((tid & 63) == 0) wred[tid >> 6] = m;
  __syncthreads();
  m = fmaxf(fmaxf(wred[0], wred[1]), fmaxf(wred[2], wred[3]));
  float x0 = exp2f((e0 - m) * L2E);
  float x1v = exp2f((e1 - m) * L2E);
  float s = x0 + x1v;
  for (int off = 32; off; off >>= 1) s += __shfl_xor(s, off);
  if ((tid & 63) == 0) wred[4 + (tid >> 6)] = s;
  __syncthreads();
  s = wred[4] + wred[5] + wred[6] + wred[7];
  float inv = 1.f / s;
  float a0 = x0 * inv, a1 = x1v * inv;
  a_t[b * 512 + tid] = a0;
  a_t[b * 512 + 256 + tid] = a1;
  cov_out[b * 512 + tid] = cov[b * 512 + tid] + a0;
  cov_out[b * 512 + 256 + tid] = cov[b * 512 + 256 + tid] + a1;
  sm[tid] = a0; sm[256 + tid] = a1;
  __syncthreads();
  // ctx
  int d = tid & 127, half = tid >> 7;
  const float* hp = h_i + ((size_t)b * 512 + half * 256) * 128 + d;
  float acc = 0.f;
#pragma unroll 8
  for (int t = 0; t < 256; ++t) acc += sm[half * 256 + t] * hp[(size_t)t * 128];
  red[tid] = acc;
  __syncthreads();
  if (tid < 128) ctx_out[b * 128 + tid] = red[tid] + red[128 + tid];
}

// ---------------------------------------------------------------------------
// K6: pv1(bf16) = [h|ctx]@V1^T + V1_b ; p_gen ; attn_dist = (1-p_gen)*a_t
// One block per b.
// ---------------------------------------------------------------------------
__global__ __launch_bounds__(256) void k6_pv1_pgen(
    const float* __restrict__ out_h, const float* __restrict__ out_c,
    const float* __restrict__ ctx, const float* __restrict__ emb,
    const int* __restrict__ x, const float* __restrict__ V1w,
    const float* __restrict__ V1b, const float* __restrict__ W2w,
    const float* __restrict__ W2b, const float* __restrict__ a_t,
    unsigned short* __restrict__ pv1bf, float* __restrict__ pgen,
    float* __restrict__ attn_out) {
  __shared__ float cat[896];  // [ctx(128) | h(128) | c(128) | xe(512)]
  __shared__ float wr_[4];
  int b = blockIdx.x, tid = threadIdx.x;
  if (tid < 128) {
    cat[tid] = ctx[b * 128 + tid];
    cat[128 + tid] = out_h[b * 128 + tid];
  } else {
    int q = tid - 128;
    cat[256 + q] = out_c[b * 128 + q];
  }
  int xb = x[b];
  for (int k = tid; k < 512; k += 256) cat[384 + k] = emb[xb * 512 + k];
  __syncthreads();
  // pv1 over [h | ctx]
  for (int f = tid; f < 384; f += 256) {
    const float* w = V1w + f * 256;
    float acc = V1b[f];
#pragma unroll 4
    for (int k = 0; k < 256; ++k) {
      float av = (k < 128) ? cat[128 + k] : cat[k - 128];
      acc += av * w[k];
    }
    pv1bf[b * 384 + f] = (unsigned short)f2bf(acc);
  }
  // p_gen over [ctx | h | c | xe]
  float p = 0.f;
  for (int k = tid; k < 896; k += 256) p += cat[k] * W2w[k];
  for (int off = 32; off; off >>= 1) p += __shfl_xor(p, off);
  if ((tid & 63) == 0) wr_[tid >> 6] = p;
  __syncthreads();
  float pg = sigmoid_f(wr_[0] + wr_[1] + wr_[2] + wr_[3] + W2b[0]);
  if (tid == 0) pgen[b] = pg;
  float om = 1.f - pg;
  attn_out[b * 512 + tid]       = om * a_t[b * 512 + tid];
  attn_out[b * 512 + 256 + tid] = om * a_t[b * 512 + 256 + tid];
}

// ---------------------------------------------------------------------------
// K7: logits = pv1 @ V2_w^T + V2_b, MFMA bf16, written into d_out final rows
// (stride VEXT_) as scratch. grid = 938 (469 n-blocks x 2 m-halves),
// block = 512 (8 waves, each wave owns 32 b-rows x 64 v-cols).
// ---------------------------------------------------------------------------
__global__ __launch_bounds__(512) void k7_vocab(
    const unsigned short* __restrict__ pv1bf, const float* __restrict__ V2w,
    const float* __restrict__ V2b, float* __restrict__ outF) {
  __shared__ unsigned short Bl[64 * 392];  // 64 v-rows x 384 k (bf16), +8 pad
  const int bx = blockIdx.x;
  const int nb = bx >> 1, mh = bx & 1;
  const int v0 = nb * 64;
  const int tid = threadIdx.x;
  // stage B tile (f32 -> bf16), coalesced along k
  {
    int vl = tid >> 3, kg = tid & 7;
    int v = v0 + vl;
    bool ok = (v < VOC_);
    const float* src = V2w + (size_t)v * 384;
    const f32x4 zf4 = {0.f, 0.f, 0.f, 0.f};
#pragma unroll
    for (int u = 0; u < 12; ++u) {
      int k = u * 32 + kg * 4;
      f32x4 w = ok ? *(const f32x4*)(src + k) : zf4;
      s16x4 bb; bb[0] = f2bf(w[0]); bb[1] = f2bf(w[1]); bb[2] = f2bf(w[2]); bb[3] = f2bf(w[3]);
      *(s16x4*)&Bl[vl * 392 + k] = bb;
    }
  }
  const int wv = tid >> 6, lane = tid & 63;
  const int lm = lane & 15, lg = lane >> 4;
  const int m0 = mh * 256 + wv * 32;
  // A fragments from global (pv1 is tiny / L2-hot)
  s16x4 afr[2][24];
#pragma unroll
  for (int mf = 0; mf < 2; ++mf)
#pragma unroll
    for (int kf = 0; kf < 24; ++kf)
      afr[mf][kf] = *(const s16x4*)&pv1bf[(m0 + mf * 16 + lm) * 384 + kf * 16 + lg * 4];
  __syncthreads();

  const f32x4 zf4 = {0.f, 0.f, 0.f, 0.f};
  for (int nt = 0; nt < 4; ++nt) {
    int nl = nt * 16 + lm;
    f32x4 acc0 = zf4, acc1 = zf4;
#pragma unroll
    for (int kf = 0; kf < 24; ++kf) {
      s16x4 bf_ = *(const s16x4*)&Bl[nl * 392 + kf * 16 + lg * 4];
      acc0 = __builtin_amdgcn_mfma_f32_16x16x16bf16_1k(afr[0][kf], bf_, acc0, 0, 0, 0);
      acc1 = __builtin_amdgcn_mfma_f32_16x16x16bf16_1k(afr[1][kf], bf_, acc1, 0, 0, 0);
    }
    int vcol = v0 + nl;
    if (vcol < VOC_) {
      float bias = V2b[vcol];
#pragma unroll
      for (int r = 0; r < 4; ++r) {
        outF[(size_t)(m0 + lg * 4 + r) * VEXT_ + vcol]      = acc0[r] + bias;
        outF[(size_t)(m0 + 16 + lg * 4 + r) * VEXT_ + vcol] = acc1[r] + bias;
      }
    }
  }
}

// ---------------------------------------------------------------------------
// K8: per-row online softmax of logits (in d_out), scale by p_gen, zero the
// 50 OOV cols, then scatter-add attn_dist via same-block atomics.
// One block (1024 thr) per b.
// ---------------------------------------------------------------------------
__global__ __launch_bounds__(1024) void k8_final(
    const float* __restrict__ pgen, const int* __restrict__ code_ext,
    const float* __restrict__ attn, float* __restrict__ outF) {
  __shared__ float lm_[16], ls_[16];
  int b = blockIdx.x, tid = threadIdx.x;
  float* row = outF + (size_t)b * VEXT_;
  float m = -3.4e38f, s = 0.f;
  for (int v = tid; v < VOC_; v += 1024) {
    float l = row[v];
    float nm = fmaxf(m, l);
    s = s * exp2f((m - nm) * L2E) + exp2f((l - nm) * L2E);
    m = nm;
  }
  for (int off = 32; off; off >>= 1) {
    float m2 = __shfl_xor(m, off), s2 = __shfl_xor(s, off);
    float nm = fmaxf(m, m2);
    s = s * exp2f((m - nm) * L2E) + s2 * exp2f((m2 - nm) * L2E);
    m = nm;
  }
  if ((tid & 63) == 0) { lm_[tid >> 6] = m; ls_[tid >> 6] = s; }
  __syncthreads();
  if (tid == 0) {
    float M = lm_[0], S = ls_[0];
    for (int i = 1; i < 16; ++i) {
      float nm = fmaxf(M, lm_[i]);
      S = S * exp2f((M - nm) * L2E) + ls_[i] * exp2f((lm_[i] - nm) * L2E);
      M = nm;
    }
    lm_[0] = M; ls_[0] = S;
  }
  __syncthreads();
  float M = lm_[0];
  float pm = pgen[b] / ls_[0];
  for (int v = tid; v < VOC_; v += 1024)
    row[v] = pm * exp2f((row[v] - M) * L2E);
  if (tid < 50) row[VOC_ + tid] = 0.f;
  __threadfence();
  __syncthreads();
  if (tid < 512) {
    int idx = code_ext[b * 512 + tid];
    atomicAdd(&row[idx], attn[b * 512 + tid]);
  }
}

// ---------------------------------------------------------------------------
extern "C" void kernel_launch(void* const* d_in, const int* in_sizes, int n_in,
                              void* d_out, int out_size, void* d_ws, size_t ws_size,
                              hipStream_t stream) {
  (void)in_sizes; (void)n_in; (void)out_size; (void)ws_size;
  const float* h_i    = (const float*)d_in[0];
  const float* h_prev = (const float*)d_in[1];
  const float* c_prev = (const float*)d_in[2];
  const float* ctxp   = (const float*)d_in[3];
  const float* cov    = (const float*)d_in[4];
  const float* emb    = (const float*)d_in[5];
  const float* Wih    = (const float*)d_in[6];
  const float* Whh    = (const float*)d_in[7];
  const float* bih    = (const float*)d_in[8];
  const float* bhh    = (const float*)d_in[9];
  const float* W1w    = (const float*)d_in[10];
  const float* W1b    = (const float*)d_in[11];
  const float* W2w    = (const float*)d_in[12];
  const float* W2b    = (const float*)d_in[13];
  const float* V1w    = (const float*)d_in[14];
  const float* V1b    = (const float*)d_in[15];
  const float* V2w    = (const float*)d_in[16];
  const float* V2b    = (const float*)d_in[17];
  const float* Whw    = (const float*)d_in[18];
  const float* Wsw    = (const float*)d_in[19];
  const float* Wsb    = (const float*)d_in[20];
  const float* Wcw    = (const float*)d_in[21];
  const float* Vw     = (const float*)d_in[22];
  const int*   x      = (const int*)d_in[23];
  const int*   code   = (const int*)d_in[24];

  float* ws    = (float*)d_ws;
  float* x1    = ws;                 // 262144
  float* gates = ws + 262144;        // 262144
  float* decf  = ws + 524288;        // 65536
  float* e_t   = ws + 589824;        // 262144
  float* a_t   = ws + 851968;        // 262144
  unsigned short* pv1bf = (unsigned short*)(ws + 1114112);  // 196608 shorts
  float* pgen  = ws + 1212416;       // 512

  float* outF  = (float*)d_out;                    // final_dist 512 x 30051
  float* attn  = outF + (size_t)512 * VEXT_;       // 262144
  float* o_h   = attn + 262144;                    // 65536
  float* o_c   = o_h + 65536;                      // 65536
  float* o_cov = o_c + 65536;                      // 262144
  float* o_ctx = o_cov + 262144;                   // 65536

  k1_x1<<<dim3(16, 16), 256, 0, stream>>>(emb, x, ctxp, W1w, W1b, x1);
  k2_gates<<<dim3(16, 16), 256, 0, stream>>>(x1, h_prev, Wih, Whh, bih, bhh, gates);
  k3_lstm<<<512, 128, 0, stream>>>(gates, c_prev, Wsw, Wsb, o_h, o_c, decf);
  k4_et<<<1024, 256, 0, stream>>>(h_i, Whw, decf, cov, Wcw, Vw, e_t);
  k5_softmax_ctx<<<512, 256, 0, stream>>>(e_t, cov, h_i, a_t, o_cov, o_ctx);
  k6_pv1_pgen<<<512, 256, 0, stream>>>(o_h, o_c, o_ctx, emb, x, V1w, V1b, W2w, W2b,
                                       a_t, pv1bf, pgen, attn);
  k7_vocab<<<938, 512, 0, stream>>>(pv1bf, V2w, V2b, outF);
  k8_final<<<512, 1024, 0, stream>>>(pgen, code, attn, outF);
}

// Round 2
// 298.447 us; speedup vs baseline: 1.6850x; 1.6850x over previous
//
#include <hip/hip_runtime.h>
#include <math.h>

// Shapes (fixed by the reference)
#define B_    512
#define T_    512
#define DEC_  128
#define EMB_  512
#define VOC_  30001
#define VEXT_ 30051   // VOC_ + 50 OOV

typedef float f32x4 __attribute__((ext_vector_type(4)));
typedef short s16x4 __attribute__((ext_vector_type(4)));

#define L2E 1.4426950408889634f

__device__ __forceinline__ float sigmoid_f(float x) {
  float xc = fminf(fmaxf(x, -30.f), 30.f);
  float t = exp2f(xc * L2E);
  return t / (1.f + t);
}
__device__ __forceinline__ float tanh_f(float x) {
  float xc = fminf(fmaxf(x, -15.f), 15.f);
  float t = exp2f(xc * (2.f * L2E));
  return (t - 1.f) / (t + 1.f);
}
// f32 -> bf16 (RNE)
__device__ __forceinline__ short f2bf(float f) {
  unsigned u = __builtin_bit_cast(unsigned, f);
  u += 0x7FFFu + ((u >> 16) & 1u);
  return (short)(u >> 16);
}

// ---------------------------------------------------------------------------
// K1: x1[b,f] = sum_k [emb[x[b]] | ctx_prev][b,k] * W1_w[f,k] + W1_b[f]
// M=512(b), N=512(f), K=640. 32x32 tiles, fp32.
// ---------------------------------------------------------------------------
__global__ __launch_bounds__(256) void k1_x1(
    const float* __restrict__ emb, const int* __restrict__ x,
    const float* __restrict__ ctxp, const float* __restrict__ W1w,
    const float* __restrict__ W1b, float* __restrict__ x1) {
  __shared__ float As[32][33];
  __shared__ float Ws[32][33];
  const int tid = threadIdx.x;
  const int f0 = blockIdx.x * 32, b0 = blockIdx.y * 32;
  const int row = tid >> 3, seg = tid & 7;
  const int tx = tid & 15, ty = tid >> 4;
  float a00 = 0.f, a01 = 0.f, a10 = 0.f, a11 = 0.f;
  for (int k0 = 0; k0 < 640; k0 += 32) {
    int k = k0 + seg * 4;
    f32x4 av;
    if (k < 512) {
      int xb = x[b0 + row];
      av = *(const f32x4*)(emb + xb * 512 + k);
    } else {
      av = *(const f32x4*)(ctxp + (b0 + row) * 128 + (k - 512));
    }
    As[row][seg * 4 + 0] = av[0]; As[row][seg * 4 + 1] = av[1];
    As[row][seg * 4 + 2] = av[2]; As[row][seg * 4 + 3] = av[3];
    f32x4 wv = *(const f32x4*)(W1w + (f0 + row) * 640 + k);
    Ws[row][seg * 4 + 0] = wv[0]; Ws[row][seg * 4 + 1] = wv[1];
    Ws[row][seg * 4 + 2] = wv[2]; Ws[row][seg * 4 + 3] = wv[3];
    __syncthreads();
#pragma unroll
    for (int kk = 0; kk < 32; ++kk) {
      float v0 = As[ty * 2][kk], v1 = As[ty * 2 + 1][kk];
      float w0 = Ws[tx * 2][kk], w1 = Ws[tx * 2 + 1][kk];
      a00 += v0 * w0; a01 += v0 * w1; a10 += v1 * w0; a11 += v1 * w1;
    }
    __syncthreads();
  }
  int fo = f0 + tx * 2, bo = b0 + ty * 2;
  x1[bo * 512 + fo]           = a00 + W1b[fo];
  x1[bo * 512 + fo + 1]       = a01 + W1b[fo + 1];
  x1[(bo + 1) * 512 + fo]     = a10 + W1b[fo];
  x1[(bo + 1) * 512 + fo + 1] = a11 + W1b[fo + 1];
}

// ---------------------------------------------------------------------------
// K2: gates[b,j] = sum [x1 | h_prev][b,k] * [W_ih | W_hh][j,k] + b_ih + b_hh
// ---------------------------------------------------------------------------
__global__ __launch_bounds__(256) void k2_gates(
    const float* __restrict__ x1, const float* __restrict__ hprev,
    const float* __restrict__ Wih, const float* __restrict__ Whh,
    const float* __restrict__ bih, const float* __restrict__ bhh,
    float* __restrict__ gates) {
  __shared__ float As[32][33];
  __shared__ float Ws[32][33];
  const int tid = threadIdx.x;
  const int f0 = blockIdx.x * 32, b0 = blockIdx.y * 32;
  const int row = tid >> 3, seg = tid & 7;
  const int tx = tid & 15, ty = tid >> 4;
  float a00 = 0.f, a01 = 0.f, a10 = 0.f, a11 = 0.f;
  for (int k0 = 0; k0 < 640; k0 += 32) {
    int k = k0 + seg * 4;
    f32x4 av, wv;
    if (k < 512) {
      av = *(const f32x4*)(x1 + (b0 + row) * 512 + k);
      wv = *(const f32x4*)(Wih + (f0 + row) * 512 + k);
    } else {
      av = *(const f32x4*)(hprev + (b0 + row) * 128 + (k - 512));
      wv = *(const f32x4*)(Whh + (f0 + row) * 128 + (k - 512));
    }
    As[row][seg * 4 + 0] = av[0]; As[row][seg * 4 + 1] = av[1];
    As[row][seg * 4 + 2] = av[2]; As[row][seg * 4 + 3] = av[3];
    Ws[row][seg * 4 + 0] = wv[0]; Ws[row][seg * 4 + 1] = wv[1];
    Ws[row][seg * 4 + 2] = wv[2]; Ws[row][seg * 4 + 3] = wv[3];
    __syncthreads();
#pragma unroll
    for (int kk = 0; kk < 32; ++kk) {
      float v0 = As[ty * 2][kk], v1 = As[ty * 2 + 1][kk];
      float w0 = Ws[tx * 2][kk], w1 = Ws[tx * 2 + 1][kk];
      a00 += v0 * w0; a01 += v0 * w1; a10 += v1 * w0; a11 += v1 * w1;
    }
    __syncthreads();
  }
  int fo = f0 + tx * 2, bo = b0 + ty * 2;
  gates[bo * 512 + fo]           = a00 + bih[fo] + bhh[fo];
  gates[bo * 512 + fo + 1]       = a01 + bih[fo + 1] + bhh[fo + 1];
  gates[(bo + 1) * 512 + fo]     = a10 + bih[fo] + bhh[fo];
  gates[(bo + 1) * 512 + fo + 1] = a11 + bih[fo + 1] + bhh[fo + 1];
}

// ---------------------------------------------------------------------------
// K3: LSTM cell + dec_f = s_t @ Ws_w^T + Ws_b.  One block per b, 128 threads.
// ---------------------------------------------------------------------------
__global__ __launch_bounds__(128) void k3_lstm(
    const float* __restrict__ gates, const float* __restrict__ cprev,
    const float* __restrict__ Wsw, const float* __restrict__ Wsb,
    float* __restrict__ out_h, float* __restrict__ out_c,
    float* __restrict__ decf) {
  __shared__ float st[256];
  int b = blockIdx.x, d = threadIdx.x;
  const float* g = gates + b * 512;
  float iv = sigmoid_f(g[d]);
  float fv = sigmoid_f(g[128 + d]);
  float gv = tanh_f(g[256 + d]);
  float ov = sigmoid_f(g[384 + d]);
  float c = fv * cprev[b * 128 + d] + iv * gv;
  float h = ov * tanh_f(c);
  out_h[b * 128 + d] = h;
  out_c[b * 128 + d] = c;
  st[d] = h; st[128 + d] = c;
  __syncthreads();
  float acc = Wsb[d];
  const float* wr = Wsw + d * 256;
#pragma unroll 4
  for (int k = 0; k < 256; ++k) acc += st[k] * wr[k];
  decf[b * 128 + d] = acc;
}

// ---------------------------------------------------------------------------
// K4: e_t[b,t] = V_w . tanh(h_i@Wh^T + dec_f[b] + cov[b,t]*Wc)
// MFMA 16x16x16 bf16 (_1k). One wave handles (b, 64 t, all 128 d).
// grid = 1024 (= B*2), block = 256 (4 waves).
// ---------------------------------------------------------------------------
__global__ __launch_bounds__(256) void k4_et(
    const float* __restrict__ h_i, const float* __restrict__ Whw,
    const float* __restrict__ decf, const float* __restrict__ cov,
    const float* __restrict__ Wcw, const float* __restrict__ Vw,
    float* __restrict__ e_t) {
  const int b = blockIdx.x >> 1;
  const int th = blockIdx.x & 1;
  const int wv = threadIdx.x >> 6;
  const int lane = threadIdx.x & 63;
  const int lm = lane & 15, lg = lane >> 4;
  const int t0 = th * 256 + wv * 64;

  // A fragments: h_i rows. afr[mf][kf]: A[i=lm][k=4*lg+e], k-tile kf (K=16)
  s16x4 afr[4][8];
#pragma unroll
  for (int mf = 0; mf < 4; ++mf) {
#pragma unroll
    for (int kf = 0; kf < 8; ++kf) {
      const float* p = h_i + (size_t)(b * 512 + t0 + mf * 16 + lm) * 128 + kf * 16 + lg * 4;
      f32x4 v = *(const f32x4*)p;
      s16x4 a; a[0] = f2bf(v[0]); a[1] = f2bf(v[1]); a[2] = f2bf(v[2]); a[3] = f2bf(v[3]);
      afr[mf][kf] = a;
    }
  }
  float dec_v[8], vw_v[8], wc_v[8];
#pragma unroll
  for (int nf = 0; nf < 8; ++nf) {
    dec_v[nf] = decf[b * 128 + nf * 16 + lm];
    vw_v[nf]  = Vw[nf * 16 + lm];
    wc_v[nf]  = Wcw[nf * 16 + lm];
  }
  float cov_v[16];
#pragma unroll
  for (int mf = 0; mf < 4; ++mf)
#pragma unroll
    for (int r = 0; r < 4; ++r)
      cov_v[mf * 4 + r] = cov[b * 512 + t0 + mf * 16 + lg * 4 + r];

  float e_acc[16];
#pragma unroll
  for (int i = 0; i < 16; ++i) e_acc[i] = 0.f;

  const f32x4 zf4 = {0.f, 0.f, 0.f, 0.f};
  for (int nf = 0; nf < 8; ++nf) {
    f32x4 acc[4];
#pragma unroll
    for (int mf = 0; mf < 4; ++mf) acc[mf] = zf4;
#pragma unroll
    for (int kf = 0; kf < 8; ++kf) {
      // B[k=4*lg+e][n=lm] = Wh_w[n][k]  (enc = h_i @ Wh^T)
      const float* q = Whw + (nf * 16 + lm) * 128 + kf * 16 + lg * 4;
      f32x4 w = *(const f32x4*)q;
      s16x4 bf_; bf_[0] = f2bf(w[0]); bf_[1] = f2bf(w[1]); bf_[2] = f2bf(w[2]); bf_[3] = f2bf(w[3]);
#pragma unroll
      for (int mf = 0; mf < 4; ++mf)
        acc[mf] = __builtin_amdgcn_mfma_f32_16x16x16bf16_1k(afr[mf][kf], bf_, acc[mf], 0, 0, 0);
    }
    // D[i=4*lg+r][j=lm]: t = t0+mf*16+4*lg+r, d = nf*16+lm
#pragma unroll
    for (int mf = 0; mf < 4; ++mf)
#pragma unroll
      for (int r = 0; r < 4; ++r) {
        float val = acc[mf][r] + dec_v[nf] + cov_v[mf * 4 + r] * wc_v[nf];
        e_acc[mf * 4 + r] += vw_v[nf] * tanh_f(val);
      }
  }
  // reduce over the 16 d-columns held across lanes lm=0..15 (same lg group)
#pragma unroll
  for (int i = 0; i < 16; ++i) {
    float v = e_acc[i];
    v += __shfl_xor(v, 1); v += __shfl_xor(v, 2);
    v += __shfl_xor(v, 4); v += __shfl_xor(v, 8);
    e_acc[i] = v;
  }
  if (lm == 0) {
#pragma unroll
    for (int mf = 0; mf < 4; ++mf)
#pragma unroll
      for (int r = 0; r < 4; ++r)
        e_t[b * 512 + t0 + mf * 16 + lg * 4 + r] = e_acc[mf * 4 + r];
  }
}

// ---------------------------------------------------------------------------
// K5: softmax over t, coverage_new, ctx = sum_t a_t * h_i. One block per b.
// ---------------------------------------------------------------------------
__global__ __launch_bounds__(256) void k5_softmax_ctx(
    const float* __restrict__ e_t, const float* __restrict__ cov,
    const float* __restrict__ h_i, float* __restrict__ a_t,
    float* __restrict__ cov_out, float* __restrict__ ctx_out) {
  __shared__ float sm[512];
  __shared__ float red[256];
  __shared__ float wred[8];
  int b = blockIdx.x, tid = threadIdx.x;
  float e0 = e_t[b * 512 + tid], e1 = e_t[b * 512 + 256 + tid];
  float m = fmaxf(e0, e1);
  for (int off = 32; off; off >>= 1) m = fmaxf(m, __shfl_xor(m, off));
  if ((tid & 63) == 0) wred[tid >> 6] = m;
  __syncthreads();
  m = fmaxf(fmaxf(wred[0], wred[1]), fmaxf(wred[2], wred[3]));
  float x0 = exp2f((e0 - m) * L2E);
  float x1v = exp2f((e1 - m) * L2E);
  float s = x0 + x1v;
  for (int off = 32; off; off >>= 1) s += __shfl_xor(s, off);
  if ((tid & 63) == 0) wred[4 + (tid >> 6)] = s;
  __syncthreads();
  s = wred[4] + wred[5] + wred[6] + wred[7];
  float inv = 1.f / s;
  float a0 = x0 * inv, a1 = x1v * inv;
  a_t[b * 512 + tid] = a0;
  a_t[b * 512 + 256 + tid] = a1;
  cov_out[b * 512 + tid] = cov[b * 512 + tid] + a0;
  cov_out[b * 512 + 256 + tid] = cov[b * 512 + 256 + tid] + a1;
  sm[tid] = a0; sm[256 + tid] = a1;
  __syncthreads();
  // ctx
  int d = tid & 127, half = tid >> 7;
  const float* hp = h_i + ((size_t)b * 512 + half * 256) * 128 + d;
  float acc = 0.f;
#pragma unroll 8
  for (int t = 0; t < 256; ++t) acc += sm[half * 256 + t] * hp[(size_t)t * 128];
  red[tid] = acc;
  __syncthreads();
  if (tid < 128) ctx_out[b * 128 + tid] = red[tid] + red[128 + tid];
}

// ---------------------------------------------------------------------------
// K6: pv1(bf16) = [h|ctx]@V1^T + V1_b ; p_gen ; attn_dist = (1-p_gen)*a_t
// One block per b.
// ---------------------------------------------------------------------------
__global__ __launch_bounds__(256) void k6_pv1_pgen(
    const float* __restrict__ out_h, const float* __restrict__ out_c,
    const float* __restrict__ ctx, const float* __restrict__ emb,
    const int* __restrict__ x, const float* __restrict__ V1w,
    const float* __restrict__ V1b, const float* __restrict__ W2w,
    const float* __restrict__ W2b, const float* __restrict__ a_t,
    unsigned short* __restrict__ pv1bf, float* __restrict__ pgen,
    float* __restrict__ attn_out) {
  __shared__ float cat[896];  // [ctx(128) | h(128) | c(128) | xe(512)]
  __shared__ float wr_[4];
  int b = blockIdx.x, tid = threadIdx.x;
  if (tid < 128) {
    cat[tid] = ctx[b * 128 + tid];
    cat[128 + tid] = out_h[b * 128 + tid];
  } else {
    int q = tid - 128;
    cat[256 + q] = out_c[b * 128 + q];
  }
  int xb = x[b];
  for (int k = tid; k < 512; k += 256) cat[384 + k] = emb[xb * 512 + k];
  __syncthreads();
  // pv1 over [h | ctx]
  for (int f = tid; f < 384; f += 256) {
    const float* w = V1w + f * 256;
    float acc = V1b[f];
#pragma unroll 4
    for (int k = 0; k < 256; ++k) {
      float av = (k < 128) ? cat[128 + k] : cat[k - 128];
      acc += av * w[k];
    }
    pv1bf[b * 384 + f] = (unsigned short)f2bf(acc);
  }
  // p_gen over [ctx | h | c | xe]
  float p = 0.f;
  for (int k = tid; k < 896; k += 256) p += cat[k] * W2w[k];
  for (int off = 32; off; off >>= 1) p += __shfl_xor(p, off);
  if ((tid & 63) == 0) wr_[tid >> 6] = p;
  __syncthreads();
  float pg = sigmoid_f(wr_[0] + wr_[1] + wr_[2] + wr_[3] + W2b[0]);
  if (tid == 0) pgen[b] = pg;
  float om = 1.f - pg;
  attn_out[b * 512 + tid]       = om * a_t[b * 512 + tid];
  attn_out[b * 512 + 256 + tid] = om * a_t[b * 512 + 256 + tid];
}

// ---------------------------------------------------------------------------
// K7: logits = pv1 @ V2_w^T + V2_b, MFMA bf16, written into d_out final rows
// (stride VEXT_) as scratch. grid = 938 (469 n-blocks x 2 m-halves),
// block = 512 (8 waves, each wave owns 32 b-rows x 64 v-cols).
// ---------------------------------------------------------------------------
__global__ __launch_bounds__(512) void k7_vocab(
    const unsigned short* __restrict__ pv1bf, const float* __restrict__ V2w,
    const float* __restrict__ V2b, float* __restrict__ outF) {
  __shared__ unsigned short Bl[64 * 392];  // 64 v-rows x 384 k (bf16), +8 pad
  const int bx = blockIdx.x;
  const int nb = bx >> 1, mh = bx & 1;
  const int v0 = nb * 64;
  const int tid = threadIdx.x;
  // stage B tile (f32 -> bf16), coalesced along k
  {
    int vl = tid >> 3, kg = tid & 7;
    int v = v0 + vl;
    bool ok = (v < VOC_);
    const float* src = V2w + (size_t)v * 384;
    const f32x4 zf4 = {0.f, 0.f, 0.f, 0.f};
#pragma unroll
    for (int u = 0; u < 12; ++u) {
      int k = u * 32 + kg * 4;
      f32x4 w = ok ? *(const f32x4*)(src + k) : zf4;
      s16x4 bb; bb[0] = f2bf(w[0]); bb[1] = f2bf(w[1]); bb[2] = f2bf(w[2]); bb[3] = f2bf(w[3]);
      *(s16x4*)&Bl[vl * 392 + k] = bb;
    }
  }
  const int wv = tid >> 6, lane = tid & 63;
  const int lm = lane & 15, lg = lane >> 4;
  const int m0 = mh * 256 + wv * 32;
  // A fragments from global (pv1 is tiny / L2-hot)
  s16x4 afr[2][24];
#pragma unroll
  for (int mf = 0; mf < 2; ++mf)
#pragma unroll
    for (int kf = 0; kf < 24; ++kf)
      afr[mf][kf] = *(const s16x4*)&pv1bf[(m0 + mf * 16 + lm) * 384 + kf * 16 + lg * 4];
  __syncthreads();

  const f32x4 zf4 = {0.f, 0.f, 0.f, 0.f};
  for (int nt = 0; nt < 4; ++nt) {
    int nl = nt * 16 + lm;
    f32x4 acc0 = zf4, acc1 = zf4;
#pragma unroll
    for (int kf = 0; kf < 24; ++kf) {
      s16x4 bf_ = *(const s16x4*)&Bl[nl * 392 + kf * 16 + lg * 4];
      acc0 = __builtin_amdgcn_mfma_f32_16x16x16bf16_1k(afr[0][kf], bf_, acc0, 0, 0, 0);
      acc1 = __builtin_amdgcn_mfma_f32_16x16x16bf16_1k(afr[1][kf], bf_, acc1, 0, 0, 0);
    }
    int vcol = v0 + nl;
    if (vcol < VOC_) {
      float bias = V2b[vcol];
#pragma unroll
      for (int r = 0; r < 4; ++r) {
        outF[(size_t)(m0 + lg * 4 + r) * VEXT_ + vcol]      = acc0[r] + bias;
        outF[(size_t)(m0 + 16 + lg * 4 + r) * VEXT_ + vcol] = acc1[r] + bias;
      }
    }
  }
}

// ---------------------------------------------------------------------------
// K8: per-row softmax of logits (in d_out), scale by p_gen, zero the 50 OOV
// cols, scatter-add attn_dist. One block (1024 thr) per row b.
//
// Design notes (round 2 rewrite):
//  - Each thread caches its ~30 logits in registers (fully unrolled -> up to
//    30 loads in flight; no loop-carried load->use chain).
//  - max-then-sum (no online rescale; independent exp2s).
//  - NO __threadfence(): the device-scope fence forced per-wave L2
//    writeback/invalidate on multi-XCD gfx950 (the 290us stall). All
//    accesses to row b come from block b (one CU -> one XCD -> one L2);
//    __syncthreads() drains vmcnt so stores are in L2; scatter uses
//    WORKGROUP-scope atomics, which execute at the local L2 and thus see
//    those stores without any cross-XCD flush.
// ---------------------------------------------------------------------------
#define K8_IT 30  // ceil(VOC_/1024)

__global__ __launch_bounds__(1024) void k8_final(
    const float* __restrict__ pgen, const int* __restrict__ code_ext,
    const float* __restrict__ attn, float* __restrict__ outF) {
  __shared__ float lm_[16], ls_[16];
  const int b = blockIdx.x, tid = threadIdx.x;
  float* row = outF + (size_t)b * VEXT_;

  float lv[K8_IT];
#pragma unroll
  for (int i = 0; i < K8_IT; ++i) {
    int v = tid + i * 1024;
    lv[i] = (v < VOC_) ? row[v] : -3.4e38f;
  }
  // block max
  float m = lv[0];
#pragma unroll
  for (int i = 1; i < K8_IT; ++i) m = fmaxf(m, lv[i]);
  for (int off = 32; off; off >>= 1) m = fmaxf(m, __shfl_xor(m, off));
  if ((tid & 63) == 0) lm_[tid >> 6] = m;
  __syncthreads();
  float M = lm_[0];
#pragma unroll
  for (int i = 1; i < 16; ++i) M = fmaxf(M, lm_[i]);
  // exp + block sum
  float s = 0.f;
#pragma unroll
  for (int i = 0; i < K8_IT; ++i) {
    lv[i] = exp2f((lv[i] - M) * L2E);  // invalid lanes: exp2(-huge) = 0
    s += lv[i];
  }
  for (int off = 32; off; off >>= 1) s += __shfl_xor(s, off);
  if ((tid & 63) == 0) ls_[tid >> 6] = s;
  __syncthreads();
  float S = 0.f;
#pragma unroll
  for (int i = 0; i < 16; ++i) S += ls_[i];
  float pm = pgen[b] / S;
  // write normalized, p_gen-scaled distribution
#pragma unroll
  for (int i = 0; i < K8_IT; ++i) {
    int v = tid + i * 1024;
    if (v < VOC_) row[v] = pm * lv[i];
  }
  if (tid < 50) row[VOC_ + tid] = 0.f;
  __syncthreads();  // drains vmcnt: all row stores are at the local L2
  if (tid < 512) {
    int idx = code_ext[b * 512 + tid];
    __hip_atomic_fetch_add(&row[idx], attn[b * 512 + tid],
                           __ATOMIC_RELAXED, __HIP_MEMORY_SCOPE_WORKGROUP);
  }
}

// ---------------------------------------------------------------------------
extern "C" void kernel_launch(void* const* d_in, const int* in_sizes, int n_in,
                              void* d_out, int out_size, void* d_ws, size_t ws_size,
                              hipStream_t stream) {
  (void)in_sizes; (void)n_in; (void)out_size; (void)ws_size;
  const float* h_i    = (const float*)d_in[0];
  const float* h_prev = (const float*)d_in[1];
  const float* c_prev = (const float*)d_in[2];
  const float* ctxp   = (const float*)d_in[3];
  const float* cov    = (const float*)d_in[4];
  const float* emb    = (const float*)d_in[5];
  const float* Wih    = (const float*)d_in[6];
  const float* Whh    = (const float*)d_in[7];
  const float* bih    = (const float*)d_in[8];
  const float* bhh    = (const float*)d_in[9];
  const float* W1w    = (const float*)d_in[10];
  const float* W1b    = (const float*)d_in[11];
  const float* W2w    = (const float*)d_in[12];
  const float* W2b    = (const float*)d_in[13];
  const float* V1w    = (const float*)d_in[14];
  const float* V1b    = (const float*)d_in[15];
  const float* V2w    = (const float*)d_in[16];
  const float* V2b    = (const float*)d_in[17];
  const float* Whw    = (const float*)d_in[18];
  const float* Wsw    = (const float*)d_in[19];
  const float* Wsb    = (const float*)d_in[20];
  const float* Wcw    = (const float*)d_in[21];
  const float* Vw     = (const float*)d_in[22];
  const int*   x      = (const int*)d_in[23];
  const int*   code   = (const int*)d_in[24];

  float* ws    = (float*)d_ws;
  float* x1    = ws;                 // 262144
  float* gates = ws + 262144;        // 262144
  float* decf  = ws + 524288;        // 65536
  float* e_t   = ws + 589824;        // 262144
  float* a_t   = ws + 851968;        // 262144
  unsigned short* pv1bf = (unsigned short*)(ws + 1114112);  // 196608 shorts
  float* pgen  = ws + 1212416;       // 512

  float* outF  = (float*)d_out;                    // final_dist 512 x 30051
  float* attn  = outF + (size_t)512 * VEXT_;       // 262144
  float* o_h   = attn + 262144;                    // 65536
  float* o_c   = o_h + 65536;                      // 65536
  float* o_cov = o_c + 65536;                      // 262144
  float* o_ctx = o_cov + 262144;                   // 65536

  k1_x1<<<dim3(16, 16), 256, 0, stream>>>(emb, x, ctxp, W1w, W1b, x1);
  k2_gates<<<dim3(16, 16), 256, 0, stream>>>(x1, h_prev, Wih, Whh, bih, bhh, gates);
  k3_lstm<<<512, 128, 0, stream>>>(gates, c_prev, Wsw, Wsb, o_h, o_c, decf);
  k4_et<<<1024, 256, 0, stream>>>(h_i, Whw, decf, cov, Wcw, Vw, e_t);
  k5_softmax_ctx<<<512, 256, 0, stream>>>(e_t, cov, h_i, a_t, o_cov, o_ctx);
  k6_pv1_pgen<<<512, 256, 0, stream>>>(o_h, o_c, o_ctx, emb, x, V1w, V1b, W2w, W2b,
                                       a_t, pv1bf, pgen, attn);
  k7_vocab<<<938, 512, 0, stream>>>(pv1bf, V2w, V2b, outF);
  k8_final<<<512, 1024, 0, stream>>>(pgen, code, attn, outF);
}

// Round 3
// 282.447 us; speedup vs baseline: 1.7804x; 1.0566x over previous
//
#include <hip/hip_runtime.h>
#include <math.h>

// Shapes (fixed by the reference)
#define B_    512
#define T_    512
#define DEC_  128
#define EMB_  512
#define VOC_  30001
#define VEXT_ 30051   // VOC_ + 50 OOV

typedef float f32x4 __attribute__((ext_vector_type(4)));
typedef short s16x4 __attribute__((ext_vector_type(4)));

#define L2E 1.4426950408889634f

__device__ __forceinline__ float sigmoid_f(float x) {
  float xc = fminf(fmaxf(x, -30.f), 30.f);
  float t = exp2f(xc * L2E);
  return t / (1.f + t);
}
__device__ __forceinline__ float tanh_f(float x) {
  float xc = fminf(fmaxf(x, -15.f), 15.f);
  float t = exp2f(xc * (2.f * L2E));
  return (t - 1.f) / (t + 1.f);
}
// f32 -> bf16 (RNE)
__device__ __forceinline__ short f2bf(float f) {
  unsigned u = __builtin_bit_cast(unsigned, f);
  u += 0x7FFFu + ((u >> 16) & 1u);
  return (short)(u >> 16);
}

// ---------------------------------------------------------------------------
// K0: convert Wh_w (128x128 f32) to bf16 MFMA B-fragments, fragment-linear:
// bw[((nf*8+kf)*64 + lane)*4 + e] = Whw[nf*16 + (lane&15)][kf*16 + (lane>>4)*4 + e]
// One coalesced s16x4 per (frag, lane) read in k4 -- no cvt on k4's path.
// ---------------------------------------------------------------------------
__global__ __launch_bounds__(256) void k0_prep(
    const float* __restrict__ Whw, unsigned short* __restrict__ bw) {
  const int t = threadIdx.x;
#pragma unroll
  for (int i = 0; i < 16; ++i) {
    int p = t + 256 * i;          // (frag, lane) pair
    int f = p >> 6, l = p & 63;
    int nf = f >> 3, kf = f & 7;
    int rowN = nf * 16 + (l & 15);
    int colK = kf * 16 + (l >> 4) * 4;
    f32x4 w = *(const f32x4*)(Whw + rowN * 128 + colK);
    s16x4 bb; bb[0] = f2bf(w[0]); bb[1] = f2bf(w[1]); bb[2] = f2bf(w[2]); bb[3] = f2bf(w[3]);
    *(s16x4*)&bw[p * 4] = bb;
  }
}

// ---------------------------------------------------------------------------
// K1: x1[b,f] = sum_k [emb[x[b]] | ctx_prev][b,k] * W1_w[f,k] + W1_b[f]
// ---------------------------------------------------------------------------
__global__ __launch_bounds__(256) void k1_x1(
    const float* __restrict__ emb, const int* __restrict__ x,
    const float* __restrict__ ctxp, const float* __restrict__ W1w,
    const float* __restrict__ W1b, float* __restrict__ x1) {
  __shared__ float As[32][33];
  __shared__ float Ws[32][33];
  const int tid = threadIdx.x;
  const int f0 = blockIdx.x * 32, b0 = blockIdx.y * 32;
  const int row = tid >> 3, seg = tid & 7;
  const int tx = tid & 15, ty = tid >> 4;
  float a00 = 0.f, a01 = 0.f, a10 = 0.f, a11 = 0.f;
  for (int k0 = 0; k0 < 640; k0 += 32) {
    int k = k0 + seg * 4;
    f32x4 av;
    if (k < 512) {
      int xb = x[b0 + row];
      av = *(const f32x4*)(emb + xb * 512 + k);
    } else {
      av = *(const f32x4*)(ctxp + (b0 + row) * 128 + (k - 512));
    }
    As[row][seg * 4 + 0] = av[0]; As[row][seg * 4 + 1] = av[1];
    As[row][seg * 4 + 2] = av[2]; As[row][seg * 4 + 3] = av[3];
    f32x4 wv = *(const f32x4*)(W1w + (f0 + row) * 640 + k);
    Ws[row][seg * 4 + 0] = wv[0]; Ws[row][seg * 4 + 1] = wv[1];
    Ws[row][seg * 4 + 2] = wv[2]; Ws[row][seg * 4 + 3] = wv[3];
    __syncthreads();
#pragma unroll
    for (int kk = 0; kk < 32; ++kk) {
      float v0 = As[ty * 2][kk], v1 = As[ty * 2 + 1][kk];
      float w0 = Ws[tx * 2][kk], w1 = Ws[tx * 2 + 1][kk];
      a00 += v0 * w0; a01 += v0 * w1; a10 += v1 * w0; a11 += v1 * w1;
    }
    __syncthreads();
  }
  int fo = f0 + tx * 2, bo = b0 + ty * 2;
  x1[bo * 512 + fo]           = a00 + W1b[fo];
  x1[bo * 512 + fo + 1]       = a01 + W1b[fo + 1];
  x1[(bo + 1) * 512 + fo]     = a10 + W1b[fo];
  x1[(bo + 1) * 512 + fo + 1] = a11 + W1b[fo + 1];
}

// ---------------------------------------------------------------------------
// K2: gates[b,j] = sum [x1 | h_prev][b,k] * [W_ih | W_hh][j,k] + b_ih + b_hh
// ---------------------------------------------------------------------------
__global__ __launch_bounds__(256) void k2_gates(
    const float* __restrict__ x1, const float* __restrict__ hprev,
    const float* __restrict__ Wih, const float* __restrict__ Whh,
    const float* __restrict__ bih, const float* __restrict__ bhh,
    float* __restrict__ gates) {
  __shared__ float As[32][33];
  __shared__ float Ws[32][33];
  const int tid = threadIdx.x;
  const int f0 = blockIdx.x * 32, b0 = blockIdx.y * 32;
  const int row = tid >> 3, seg = tid & 7;
  const int tx = tid & 15, ty = tid >> 4;
  float a00 = 0.f, a01 = 0.f, a10 = 0.f, a11 = 0.f;
  for (int k0 = 0; k0 < 640; k0 += 32) {
    int k = k0 + seg * 4;
    f32x4 av, wv;
    if (k < 512) {
      av = *(const f32x4*)(x1 + (b0 + row) * 512 + k);
      wv = *(const f32x4*)(Wih + (f0 + row) * 512 + k);
    } else {
      av = *(const f32x4*)(hprev + (b0 + row) * 128 + (k - 512));
      wv = *(const f32x4*)(Whh + (f0 + row) * 128 + (k - 512));
    }
    As[row][seg * 4 + 0] = av[0]; As[row][seg * 4 + 1] = av[1];
    As[row][seg * 4 + 2] = av[2]; As[row][seg * 4 + 3] = av[3];
    Ws[row][seg * 4 + 0] = wv[0]; Ws[row][seg * 4 + 1] = wv[1];
    Ws[row][seg * 4 + 2] = wv[2]; Ws[row][seg * 4 + 3] = wv[3];
    __syncthreads();
#pragma unroll
    for (int kk = 0; kk < 32; ++kk) {
      float v0 = As[ty * 2][kk], v1 = As[ty * 2 + 1][kk];
      float w0 = Ws[tx * 2][kk], w1 = Ws[tx * 2 + 1][kk];
      a00 += v0 * w0; a01 += v0 * w1; a10 += v1 * w0; a11 += v1 * w1;
    }
    __syncthreads();
  }
  int fo = f0 + tx * 2, bo = b0 + ty * 2;
  gates[bo * 512 + fo]           = a00 + bih[fo] + bhh[fo];
  gates[bo * 512 + fo + 1]       = a01 + bih[fo + 1] + bhh[fo + 1];
  gates[(bo + 1) * 512 + fo]     = a10 + bih[fo] + bhh[fo];
  gates[(bo + 1) * 512 + fo + 1] = a11 + bih[fo + 1] + bhh[fo + 1];
}

// ---------------------------------------------------------------------------
// K3: LSTM cell + dec_f = s_t @ Ws_w^T + Ws_b.  One block per b, 128 threads.
// ---------------------------------------------------------------------------
__global__ __launch_bounds__(128) void k3_lstm(
    const float* __restrict__ gates, const float* __restrict__ cprev,
    const float* __restrict__ Wsw, const float* __restrict__ Wsb,
    float* __restrict__ out_h, float* __restrict__ out_c,
    float* __restrict__ decf) {
  __shared__ float st[256];
  int b = blockIdx.x, d = threadIdx.x;
  const float* g = gates + b * 512;
  float iv = sigmoid_f(g[d]);
  float fv = sigmoid_f(g[128 + d]);
  float gv = tanh_f(g[256 + d]);
  float ov = sigmoid_f(g[384 + d]);
  float c = fv * cprev[b * 128 + d] + iv * gv;
  float h = ov * tanh_f(c);
  out_h[b * 128 + d] = h;
  out_c[b * 128 + d] = c;
  st[d] = h; st[128 + d] = c;
  __syncthreads();
  float acc = Wsb[d];
  const float* wr = Wsw + d * 256;
#pragma unroll 4
  for (int k = 0; k < 256; ++k) acc += st[k] * wr[k];
  decf[b * 128 + d] = acc;
}

// ---------------------------------------------------------------------------
// K4 v2: e_t[b,t] = V_w . tanh(h_i@Wh^T + dec_f[b] + cov[b,t]*Wc)
// B-operand (Wh_w) comes pre-converted, fragment-linear from k0_prep: one
// coalesced s16x4 load per frag, no cvt in the MFMA stream. grid = B*4 = 2048
// blocks (4 waves each), wave owns 32 t x all 128 d.
// ---------------------------------------------------------------------------
__global__ __launch_bounds__(256, 4) void k4_et(
    const float* __restrict__ h_i, const unsigned short* __restrict__ bw,
    const float* __restrict__ decf, const float* __restrict__ cov,
    const float* __restrict__ Wcw, const float* __restrict__ Vw,
    float* __restrict__ e_t) {
  const int b = blockIdx.x >> 2;
  const int q = blockIdx.x & 3;
  const int wv = threadIdx.x >> 6;
  const int lane = threadIdx.x & 63;
  const int lm = lane & 15, lg = lane >> 4;
  const int t0 = q * 128 + wv * 32;

  // A fragments: afr[mf][kf] = h_i[t = t0+mf*16+lm][k = kf*16+lg*4 + e]
  s16x4 afr[2][8];
#pragma unroll
  for (int mf = 0; mf < 2; ++mf) {
#pragma unroll
    for (int kf = 0; kf < 8; ++kf) {
      const float* p = h_i + (size_t)(b * 512 + t0 + mf * 16 + lm) * 128 + kf * 16 + lg * 4;
      f32x4 v = *(const f32x4*)p;
      s16x4 a; a[0] = f2bf(v[0]); a[1] = f2bf(v[1]); a[2] = f2bf(v[2]); a[3] = f2bf(v[3]);
      afr[mf][kf] = a;
    }
  }
  float dec_v[8], vw_v[8], wc_v[8];
#pragma unroll
  for (int nf = 0; nf < 8; ++nf) {
    dec_v[nf] = decf[b * 128 + nf * 16 + lm];
    vw_v[nf]  = Vw[nf * 16 + lm];
    wc_v[nf]  = Wcw[nf * 16 + lm];
  }
  float cov_v[8];
#pragma unroll
  for (int mf = 0; mf < 2; ++mf)
#pragma unroll
    for (int r = 0; r < 4; ++r)
      cov_v[mf * 4 + r] = cov[b * 512 + t0 + mf * 16 + lg * 4 + r];

  float e_acc[8];
#pragma unroll
  for (int i = 0; i < 8; ++i) e_acc[i] = 0.f;

  const f32x4 zf4 = {0.f, 0.f, 0.f, 0.f};
#pragma unroll
  for (int nf = 0; nf < 8; ++nf) {
    s16x4 bfr[8];
#pragma unroll
    for (int kf = 0; kf < 8; ++kf)
      bfr[kf] = *(const s16x4*)&bw[(((nf * 8 + kf) * 64) + lane) * 4];
    f32x4 acc0 = zf4, acc1 = zf4;
#pragma unroll
    for (int kf = 0; kf < 8; ++kf) {
      acc0 = __builtin_amdgcn_mfma_f32_16x16x16bf16_1k(afr[0][kf], bfr[kf], acc0, 0, 0, 0);
      acc1 = __builtin_amdgcn_mfma_f32_16x16x16bf16_1k(afr[1][kf], bfr[kf], acc1, 0, 0, 0);
    }
    // D[i=4*lg+r][j=lm]: t = t0+mf*16+4*lg+r, d = nf*16+lm
#pragma unroll
    for (int r = 0; r < 4; ++r) {
      float v0 = acc0[r] + dec_v[nf] + cov_v[r] * wc_v[nf];
      e_acc[r] += vw_v[nf] * tanh_f(v0);
      float v1 = acc1[r] + dec_v[nf] + cov_v[4 + r] * wc_v[nf];
      e_acc[4 + r] += vw_v[nf] * tanh_f(v1);
    }
  }
  // reduce over the 16 d-columns held across lanes lm=0..15 (same lg group)
#pragma unroll
  for (int i = 0; i < 8; ++i) {
    float v = e_acc[i];
    v += __shfl_xor(v, 1); v += __shfl_xor(v, 2);
    v += __shfl_xor(v, 4); v += __shfl_xor(v, 8);
    e_acc[i] = v;
  }
  if (lm == 0) {
#pragma unroll
    for (int mf = 0; mf < 2; ++mf)
#pragma unroll
      for (int r = 0; r < 4; ++r)
        e_t[b * 512 + t0 + mf * 16 + lg * 4 + r] = e_acc[mf * 4 + r];
  }
}

// ---------------------------------------------------------------------------
// K5: softmax over t, coverage_new, ctx = sum_t a_t * h_i. One block per b.
// ctx loop vectorized: thread (tg, j) accumulates f32x4 over t = tg, tg+8, ...
// ---------------------------------------------------------------------------
__global__ __launch_bounds__(256) void k5_softmax_ctx(
    const float* __restrict__ e_t, const float* __restrict__ cov,
    const float* __restrict__ h_i, float* __restrict__ a_t,
    float* __restrict__ cov_out, float* __restrict__ ctx_out) {
  __shared__ float sm[512];
  __shared__ float red[1024];
  __shared__ float wred[8];
  int b = blockIdx.x, tid = threadIdx.x;
  float e0 = e_t[b * 512 + tid], e1 = e_t[b * 512 + 256 + tid];
  float m = fmaxf(e0, e1);
  for (int off = 32; off; off >>= 1) m = fmaxf(m, __shfl_xor(m, off));
  if ((tid & 63) == 0) wred[tid >> 6] = m;
  __syncthreads();
  m = fmaxf(fmaxf(wred[0], wred[1]), fmaxf(wred[2], wred[3]));
  float x0 = exp2f((e0 - m) * L2E);
  float x1v = exp2f((e1 - m) * L2E);
  float s = x0 + x1v;
  for (int off = 32; off; off >>= 1) s += __shfl_xor(s, off);
  if ((tid & 63) == 0) wred[4 + (tid >> 6)] = s;
  __syncthreads();
  s = wred[4] + wred[5] + wred[6] + wred[7];
  float inv = 1.f / s;
  float a0 = x0 * inv, a1 = x1v * inv;
  a_t[b * 512 + tid] = a0;
  a_t[b * 512 + 256 + tid] = a1;
  cov_out[b * 512 + tid] = cov[b * 512 + tid] + a0;
  cov_out[b * 512 + 256 + tid] = cov[b * 512 + 256 + tid] + a1;
  sm[tid] = a0; sm[256 + tid] = a1;
  __syncthreads();
  // ctx: thread = (tg = tid>>5, j = tid&31); d-range j*4..j*4+3
  int j = tid & 31, tg = tid >> 5;
  const float* hb = h_i + (size_t)b * 512 * 128 + j * 4;
  f32x4 acc = {0.f, 0.f, 0.f, 0.f};
#pragma unroll 8
  for (int t = tg; t < 512; t += 8) {
    float a = sm[t];
    f32x4 hv = *(const f32x4*)(hb + (size_t)t * 128);
    acc += hv * a;
  }
  *(f32x4*)&red[tid * 4] = acc;
  __syncthreads();
  if (tid < 128) {
    float sacc = 0.f;
#pragma unroll
    for (int g = 0; g < 8; ++g) sacc += red[g * 128 + tid];
    ctx_out[b * 128 + tid] = sacc;
  }
}

// ---------------------------------------------------------------------------
// K6: pv1(bf16) = [h|ctx]@V1^T + V1_b ; p_gen ; attn_dist = (1-p_gen)*a_t
// One block per b.
// ---------------------------------------------------------------------------
__global__ __launch_bounds__(256) void k6_pv1_pgen(
    const float* __restrict__ out_h, const float* __restrict__ out_c,
    const float* __restrict__ ctx, const float* __restrict__ emb,
    const int* __restrict__ x, const float* __restrict__ V1w,
    const float* __restrict__ V1b, const float* __restrict__ W2w,
    const float* __restrict__ W2b, const float* __restrict__ a_t,
    unsigned short* __restrict__ pv1bf, float* __restrict__ pgen,
    float* __restrict__ attn_out) {
  __shared__ float cat[896];  // [ctx(128) | h(128) | c(128) | xe(512)]
  __shared__ float wr_[4];
  int b = blockIdx.x, tid = threadIdx.x;
  if (tid < 128) {
    cat[tid] = ctx[b * 128 + tid];
    cat[128 + tid] = out_h[b * 128 + tid];
  } else {
    int q = tid - 128;
    cat[256 + q] = out_c[b * 128 + q];
  }
  int xb = x[b];
  for (int k = tid; k < 512; k += 256) cat[384 + k] = emb[xb * 512 + k];
  __syncthreads();
  // pv1 over [h | ctx]
  for (int f = tid; f < 384; f += 256) {
    const float* w = V1w + f * 256;
    float acc = V1b[f];
#pragma unroll 4
    for (int k = 0; k < 256; ++k) {
      float av = (k < 128) ? cat[128 + k] : cat[k - 128];
      acc += av * w[k];
    }
    pv1bf[b * 384 + f] = (unsigned short)f2bf(acc);
  }
  // p_gen over [ctx | h | c | xe]
  float p = 0.f;
  for (int k = tid; k < 896; k += 256) p += cat[k] * W2w[k];
  for (int off = 32; off; off >>= 1) p += __shfl_xor(p, off);
  if ((tid & 63) == 0) wr_[tid >> 6] = p;
  __syncthreads();
  float pg = sigmoid_f(wr_[0] + wr_[1] + wr_[2] + wr_[3] + W2b[0]);
  if (tid == 0) pgen[b] = pg;
  float om = 1.f - pg;
  attn_out[b * 512 + tid]       = om * a_t[b * 512 + tid];
  attn_out[b * 512 + 256 + tid] = om * a_t[b * 512 + 256 + tid];
}

// ---------------------------------------------------------------------------
// K7: logits = pv1 @ V2_w^T + V2_b, MFMA bf16, written into d_out final rows
// (stride VEXT_) as scratch. grid = 938, block = 512.
// ---------------------------------------------------------------------------
__global__ __launch_bounds__(512) void k7_vocab(
    const unsigned short* __restrict__ pv1bf, const float* __restrict__ V2w,
    const float* __restrict__ V2b, float* __restrict__ outF) {
  __shared__ unsigned short Bl[64 * 392];  // 64 v-rows x 384 k (bf16), +8 pad
  const int bx = blockIdx.x;
  const int nb = bx >> 1, mh = bx & 1;
  const int v0 = nb * 64;
  const int tid = threadIdx.x;
  // stage B tile (f32 -> bf16), coalesced along k
  {
    int vl = tid >> 3, kg = tid & 7;
    int v = v0 + vl;
    bool ok = (v < VOC_);
    const float* src = V2w + (size_t)v * 384;
    const f32x4 zf4 = {0.f, 0.f, 0.f, 0.f};
#pragma unroll
    for (int u = 0; u < 12; ++u) {
      int k = u * 32 + kg * 4;
      f32x4 w = ok ? *(const f32x4*)(src + k) : zf4;
      s16x4 bb; bb[0] = f2bf(w[0]); bb[1] = f2bf(w[1]); bb[2] = f2bf(w[2]); bb[3] = f2bf(w[3]);
      *(s16x4*)&Bl[vl * 392 + k] = bb;
    }
  }
  const int wv = tid >> 6, lane = tid & 63;
  const int lm = lane & 15, lg = lane >> 4;
  const int m0 = mh * 256 + wv * 32;
  // A fragments from global (pv1 is tiny / L2-hot)
  s16x4 afr[2][24];
#pragma unroll
  for (int mf = 0; mf < 2; ++mf)
#pragma unroll
    for (int kf = 0; kf < 24; ++kf)
      afr[mf][kf] = *(const s16x4*)&pv1bf[(m0 + mf * 16 + lm) * 384 + kf * 16 + lg * 4];
  __syncthreads();

  const f32x4 zf4 = {0.f, 0.f, 0.f, 0.f};
  for (int nt = 0; nt < 4; ++nt) {
    int nl = nt * 16 + lm;
    f32x4 acc0 = zf4, acc1 = zf4;
#pragma unroll
    for (int kf = 0; kf < 24; ++kf) {
      s16x4 bf_ = *(const s16x4*)&Bl[nl * 392 + kf * 16 + lg * 4];
      acc0 = __builtin_amdgcn_mfma_f32_16x16x16bf16_1k(afr[0][kf], bf_, acc0, 0, 0, 0);
      acc1 = __builtin_amdgcn_mfma_f32_16x16x16bf16_1k(afr[1][kf], bf_, acc1, 0, 0, 0);
    }
    int vcol = v0 + nl;
    if (vcol < VOC_) {
      float bias = V2b[vcol];
#pragma unroll
      for (int r = 0; r < 4; ++r) {
        outF[(size_t)(m0 + lg * 4 + r) * VEXT_ + vcol]      = acc0[r] + bias;
        outF[(size_t)(m0 + 16 + lg * 4 + r) * VEXT_ + vcol] = acc1[r] + bias;
      }
    }
  }
}

// ---------------------------------------------------------------------------
// K8: per-row softmax of logits (in d_out), scale by p_gen, zero the 50 OOV
// cols, scatter-add attn_dist with WORKGROUP-scope atomics (no device fence:
// all accesses to row b come from block b -> one L2). One block per b.
// ---------------------------------------------------------------------------
#define K8_IT 30  // ceil(VOC_/1024)

__global__ __launch_bounds__(1024) void k8_final(
    const float* __restrict__ pgen, const int* __restrict__ code_ext,
    const float* __restrict__ attn, float* __restrict__ outF) {
  __shared__ float lm_[16], ls_[16];
  const int b = blockIdx.x, tid = threadIdx.x;
  float* row = outF + (size_t)b * VEXT_;

  float lv[K8_IT];
#pragma unroll
  for (int i = 0; i < K8_IT; ++i) {
    int v = tid + i * 1024;
    lv[i] = (v < VOC_) ? row[v] : -3.4e38f;
  }
  float m = lv[0];
#pragma unroll
  for (int i = 1; i < K8_IT; ++i) m = fmaxf(m, lv[i]);
  for (int off = 32; off; off >>= 1) m = fmaxf(m, __shfl_xor(m, off));
  if ((tid & 63) == 0) lm_[tid >> 6] = m;
  __syncthreads();
  float M = lm_[0];
#pragma unroll
  for (int i = 1; i < 16; ++i) M = fmaxf(M, lm_[i]);
  float s = 0.f;
#pragma unroll
  for (int i = 0; i < K8_IT; ++i) {
    lv[i] = exp2f((lv[i] - M) * L2E);  // invalid lanes: exp2(-huge) = 0
    s += lv[i];
  }
  for (int off = 32; off; off >>= 1) s += __shfl_xor(s, off);
  if ((tid & 63) == 0) ls_[tid >> 6] = s;
  __syncthreads();
  float S = 0.f;
#pragma unroll
  for (int i = 0; i < 16; ++i) S += ls_[i];
  float pm = pgen[b] / S;
#pragma unroll
  for (int i = 0; i < K8_IT; ++i) {
    int v = tid + i * 1024;
    if (v < VOC_) row[v] = pm * lv[i];
  }
  if (tid < 50) row[VOC_ + tid] = 0.f;
  __syncthreads();  // drains vmcnt: all row stores are at the local L2
  if (tid < 512) {
    int idx = code_ext[b * 512 + tid];
    __hip_atomic_fetch_add(&row[idx], attn[b * 512 + tid],
                           __ATOMIC_RELAXED, __HIP_MEMORY_SCOPE_WORKGROUP);
  }
}

// ---------------------------------------------------------------------------
extern "C" void kernel_launch(void* const* d_in, const int* in_sizes, int n_in,
                              void* d_out, int out_size, void* d_ws, size_t ws_size,
                              hipStream_t stream) {
  (void)in_sizes; (void)n_in; (void)out_size; (void)ws_size;
  const float* h_i    = (const float*)d_in[0];
  const float* h_prev = (const float*)d_in[1];
  const float* c_prev = (const float*)d_in[2];
  const float* ctxp   = (const float*)d_in[3];
  const float* cov    = (const float*)d_in[4];
  const float* emb    = (const float*)d_in[5];
  const float* Wih    = (const float*)d_in[6];
  const float* Whh    = (const float*)d_in[7];
  const float* bih    = (const float*)d_in[8];
  const float* bhh    = (const float*)d_in[9];
  const float* W1w    = (const float*)d_in[10];
  const float* W1b    = (const float*)d_in[11];
  const float* W2w    = (const float*)d_in[12];
  const float* W2b    = (const float*)d_in[13];
  const float* V1w    = (const float*)d_in[14];
  const float* V1b    = (const float*)d_in[15];
  const float* V2w    = (const float*)d_in[16];
  const float* V2b    = (const float*)d_in[17];
  const float* Whw    = (const float*)d_in[18];
  const float* Wsw    = (const float*)d_in[19];
  const float* Wsb    = (const float*)d_in[20];
  const float* Wcw    = (const float*)d_in[21];
  const float* Vw     = (const float*)d_in[22];
  const int*   x      = (const int*)d_in[23];
  const int*   code   = (const int*)d_in[24];

  float* ws    = (float*)d_ws;
  float* x1    = ws;                 // 262144
  float* gates = ws + 262144;        // 262144
  float* decf  = ws + 524288;        // 65536
  float* e_t   = ws + 589824;        // 262144
  float* a_t   = ws + 851968;        // 262144
  unsigned short* pv1bf = (unsigned short*)(ws + 1114112);  // 196608 shorts
  float* pgen  = ws + 1212416;       // 512
  // bw (bf16 Wh_w fragments, 16384 ushorts) aliases the a_t region: bw lives
  // k0..k4; a_t is first written in k5. No overlap in time.
  unsigned short* bw = (unsigned short*)(ws + 851968);

  float* outF  = (float*)d_out;                    // final_dist 512 x 30051
  float* attn  = outF + (size_t)512 * VEXT_;       // 262144
  float* o_h   = attn + 262144;                    // 65536
  float* o_c   = o_h + 65536;                      // 65536
  float* o_cov = o_c + 65536;                      // 262144
  float* o_ctx = o_cov + 262144;                   // 65536

  k0_prep<<<1, 256, 0, stream>>>(Whw, bw);
  k1_x1<<<dim3(16, 16), 256, 0, stream>>>(emb, x, ctxp, W1w, W1b, x1);
  k2_gates<<<dim3(16, 16), 256, 0, stream>>>(x1, h_prev, Wih, Whh, bih, bhh, gates);
  k3_lstm<<<512, 128, 0, stream>>>(gates, c_prev, Wsw, Wsb, o_h, o_c, decf);
  k4_et<<<2048, 256, 0, stream>>>(h_i, bw, decf, cov, Wcw, Vw, e_t);
  k5_softmax_ctx<<<512, 256, 0, stream>>>(e_t, cov, h_i, a_t, o_cov, o_ctx);
  k6_pv1_pgen<<<512, 256, 0, stream>>>(o_h, o_c, o_ctx, emb, x, V1w, V1b, W2w, W2b,
                                       a_t, pv1bf, pgen, attn);
  k7_vocab<<<938, 512, 0, stream>>>(pv1bf, V2w, V2b, outF);
  k8_final<<<512, 1024, 0, stream>>>(pgen, code, attn, outF);
}